// Round 12
// baseline (83.913 us; speedup 1.0000x reference)
//
#include <hip/hip_runtime.h>
#include <hip/hip_bf16.h>

typedef __attribute__((ext_vector_type(8))) short bf16x8;
typedef __attribute__((ext_vector_type(4))) float f32x4;

#define D_DIM 256   // input feature dim
#define H_DIM 128   // hidden dim per branch
#define SHIFT 10    // rows per bucket = 1024
#define NBINS 64    // covers rows < 65536
#define RPB   1024  // 1 << SHIFT
#define TILE  2048  // edges per k2s block (1024 thr x 2)

// RNE float->bf16 (bit pattern)
__device__ inline ushort f2bf(float f) {
    union { float f; unsigned u; } a; a.f = f;
    unsigned r = a.u + 0x7fffu + ((a.u >> 16) & 1u);
    return (ushort)(r >> 16);
}

// K0: build Wt bf16 [hcat][k]; zero bucket counters.
__global__ void k0_init(const float* __restrict__ W_nb, const float* __restrict__ W_self,
                        ushort* __restrict__ Wt, unsigned* __restrict__ cnt) {
    int i = blockIdx.x * 256 + threadIdx.x;
    if (i < 2 * H_DIM * D_DIM) {
        int sel = i >> 15;
        int r   = i & 32767;
        int k   = r >> 7;
        int h   = r & 127;
        const float* W = sel ? W_self : W_nb;
        Wt[(sel * H_DIM + h) * D_DIM + k] = f2bf(W[k * H_DIM + h]);
    }
    if (i < NBINS) cnt[i] = 0u;
}

// K1: persistent-B fused GEMM (R6 form — measured best).
__global__ __launch_bounds__(512, 2) void k1_gemm(
    const float* __restrict__ x, const ushort* __restrict__ Wt,
    const float* __restrict__ b_nb, const float* __restrict__ b_self,
    const float* __restrict__ W_att,
    float* __restrict__ g_nb, float* __restrict__ g_self, int N, int ntiles)
{
    __shared__ __align__(16) ushort A_lds[64][264];
    __shared__ float part[2][2][64];

    const int t    = threadIdx.x;
    const int lane = t & 63;
    const int w    = t >> 6;
    const int rh   = w >> 2;
    const int cg   = w & 3;
    const int br   = cg >> 1;
    const int ch   = cg & 1;
    const int li   = lane & 15;
    const int grp  = lane >> 4;

    float bias[4], aw[4];
    #pragma unroll
    for (int ni = 0; ni < 4; ni++) {
        int hh = ch * 64 + ni * 16 + li;
        bias[ni] = br ? b_self[hh] : b_nb[hh];
        aw[ni]   = W_att[br * H_DIM + hh];
    }

    bf16x8 Bf[4][8];
    #pragma unroll
    for (int ni = 0; ni < 4; ni++)
        #pragma unroll
        for (int ks = 0; ks < 8; ks++)
            Bf[ni][ks] = *reinterpret_cast<const bf16x8*>(
                Wt + (size_t)(cg * 64 + ni * 16 + li) * D_DIM + ks * 32 + grp * 8);

    const int sr = t >> 3;
    const int sc = t & 7;

    for (int rt = blockIdx.x; rt < ntiles; rt += gridDim.x) {
        const int row0 = rt * 64;

        __syncthreads();
        {
            const int gr = row0 + sr;
            const bool v = gr < N;
            const float4* src = reinterpret_cast<const float4*>(x + (size_t)gr * D_DIM);
            #pragma unroll
            for (int j = 0; j < 8; j++) {
                int c4 = sc + j * 8;
                ushort4 o;
                if (v) {
                    float4 f = src[c4];
                    o.x = f2bf(f.x); o.y = f2bf(f.y); o.z = f2bf(f.z); o.w = f2bf(f.w);
                } else { o.x = 0; o.y = 0; o.z = 0; o.w = 0; }
                *reinterpret_cast<ushort4*>(&A_lds[sr][c4 * 4]) = o;
            }
        }
        __syncthreads();

        f32x4 acc[2][4];
        #pragma unroll
        for (int mi = 0; mi < 2; mi++)
            #pragma unroll
            for (int ni = 0; ni < 4; ni++) acc[mi][ni] = f32x4{0.f, 0.f, 0.f, 0.f};

        #pragma unroll
        for (int ks = 0; ks < 8; ks++) {
            bf16x8 af0 = *reinterpret_cast<const bf16x8*>(&A_lds[rh * 32 + li][ks * 32 + grp * 8]);
            bf16x8 af1 = *reinterpret_cast<const bf16x8*>(&A_lds[rh * 32 + 16 + li][ks * 32 + grp * 8]);
            #pragma unroll
            for (int ni = 0; ni < 4; ni++) {
                acc[0][ni] = __builtin_amdgcn_mfma_f32_16x16x32_bf16(af0, Bf[ni][ks], acc[0][ni], 0, 0, 0);
                acc[1][ni] = __builtin_amdgcn_mfma_f32_16x16x32_bf16(af1, Bf[ni][ks], acc[1][ni], 0, 0, 0);
            }
        }

        float p[2][4];
        #pragma unroll
        for (int mi = 0; mi < 2; mi++)
            #pragma unroll
            for (int r4 = 0; r4 < 4; r4++) p[mi][r4] = 0.f;
        #pragma unroll
        for (int ni = 0; ni < 4; ni++)
            #pragma unroll
            for (int mi = 0; mi < 2; mi++)
                #pragma unroll
                for (int r4 = 0; r4 < 4; r4++) {
                    float y = acc[mi][ni][r4] + bias[ni];
                    y = y > 0.f ? y : 0.f;
                    p[mi][r4] += y * aw[ni];
                }
        #pragma unroll
        for (int mi = 0; mi < 2; mi++)
            #pragma unroll
            for (int r4 = 0; r4 < 4; r4++) {
                float v = p[mi][r4];
                #pragma unroll
                for (int m = 1; m < 16; m <<= 1) v += __shfl_xor(v, m);
                if (li == 0)
                    part[br][ch][rh * 32 + mi * 16 + grp * 4 + r4] = v;
            }
        __syncthreads();

        if (t < 128) {
            int b_ = t >> 6, lr = t & 63;
            int gr = row0 + lr;
            if (gr < N) {
                float val = part[b_][0][lr] + part[b_][1][lr];
                if (b_) g_self[gr] = val; else g_nb[gr] = val;
            }
        }
    }
}

// P1: bucket histogram of row (counts ALL edges; capacity upper bound).
__global__ __launch_bounds__(256) void p1_count(
    const int* __restrict__ row, unsigned* __restrict__ cnt, int E)
{
    __shared__ unsigned h[NBINS];
    const int t = threadIdx.x;
    if (t < NBINS) h[t] = 0;
    __syncthreads();
    for (int i = blockIdx.x * 256 + t; i < E; i += gridDim.x * 256)
        atomicAdd(&h[row[i] >> SHIFT], 1u);
    __syncthreads();
    if (t < NBINS && h[t]) atomicAdd(&cnt[t], h[t]);
}

// P2: exclusive scan -> bstart (region bases); gcur = running cursors.
__global__ void p2_scan(const unsigned* __restrict__ cnt,
                        unsigned* __restrict__ bstart, unsigned* __restrict__ gcur)
{
    if (threadIdx.x == 0) {
        unsigned run = 0;
        for (int b = 0; b < NBINS; b++) { bstart[b] = run; gcur[b] = run; run += cnt[b]; }
        bstart[NBINS] = run;
    }
}

// K2S: gate+mask -> out (coalesced); tile-sort (LDS) nonzero (row,m) records into
// bucket-major order; flush as run-coalesced global stores. Only 64 cursor
// atomics per 2048-edge tile.
__global__ __launch_bounds__(1024, 2) void k2s_gate_sort(
    const int* __restrict__ row, const int* __restrict__ col,
    const float* __restrict__ values, const float* __restrict__ noise,
    const float* __restrict__ g_nb, const float* __restrict__ g_self,
    const float* __restrict__ b_att,
    float* __restrict__ out, uint2* __restrict__ spill, unsigned* __restrict__ gcur,
    int E)
{
    __shared__ uint2 rec[TILE];
    __shared__ unsigned char bkt[TILE];
    __shared__ unsigned hcnt[NBINS];
    __shared__ unsigned binst[NBINS + 1];
    __shared__ unsigned gbase[NBINS];

    const int t    = threadIdx.x;
    const int base = blockIdx.x * TILE;

    if (t < NBINS) hcnt[t] = 0;
    __syncthreads();

    const float ba = b_att[0];
    int   rr[2]; float mm[2]; unsigned pos[2]; int bb[2]; bool keep[2];

    #pragma unroll
    for (int s = 0; s < 2; s++) {
        int e = base + s * 1024 + t;
        keep[s] = false;
        if (e < E) {
            int   r = row[e], c = col[e];
            float v = values[e];
            float u = noise[e] + 1e-7f;
            float la = g_nb[r] + g_self[c] + ba;
            float gate = u / (u + (1.f - u) * __expf(-la));
            float mask = fminf(fmaxf(gate * 1.6f - 0.5f, 0.f), 1.f);
            float m = v * mask;
            out[e] = m;
            if (m != 0.f) {
                rr[s] = r; mm[s] = m; bb[s] = r >> SHIFT;
                pos[s] = atomicAdd(&hcnt[bb[s]], 1u);
                keep[s] = true;
            }
        }
    }
    __syncthreads();

    if (t == 0) {
        unsigned run = 0;
        #pragma unroll
        for (int b = 0; b < NBINS; b++) { binst[b] = run; run += hcnt[b]; }
        binst[NBINS] = run;
    }
    __syncthreads();

    if (t < NBINS) gbase[t] = hcnt[t] ? atomicAdd(&gcur[t], hcnt[t]) : 0u;

    #pragma unroll
    for (int s = 0; s < 2; s++) {
        if (keep[s]) {
            unsigned slot = binst[bb[s]] + pos[s];
            rec[slot] = make_uint2((unsigned)rr[s], __float_as_uint(mm[s]));
            bkt[slot] = (unsigned char)bb[s];
        }
    }
    __syncthreads();

    const unsigned nrec = binst[NBINS];
    for (unsigned slot = t; slot < nrec; slot += 1024) {
        unsigned b   = bkt[slot];
        unsigned dst = gbase[b] + (slot - binst[b]);
        spill[dst] = rec[slot];
    }
}

// K2R: per-bucket LDS accumulate; dis[n] = rsqrt(1e-10 + sum). Reads
// [bstart[b], gcur[b]) — gcur holds each bucket's end after k2s.
__global__ __launch_bounds__(1024, 1) void k2r_reduce(
    const uint2* __restrict__ spill, const unsigned* __restrict__ bstart,
    const unsigned* __restrict__ gcur, float* __restrict__ dis, int N)
{
    __shared__ float acc[RPB];
    const int b = blockIdx.x, t = threadIdx.x;
    acc[t] = 0.f;
    __syncthreads();
    const unsigned s = bstart[b];
    const unsigned e = gcur[b];
    const int lo = b << SHIFT;
    for (unsigned i = s + t; i < e; i += 1024) {
        uint2 r = spill[i];
        atomicAdd(&acc[(int)r.x - lo], __uint_as_float(r.y));
    }
    __syncthreads();
    int n = lo + t;
    if (n < N) dis[n] = rsqrtf(1e-10f + acc[t]);
}

// K3: symmetric degree normalization (R10 form).
__global__ __launch_bounds__(256) void k3_edge2(
    const int* __restrict__ row, const int* __restrict__ col,
    float* __restrict__ out, const float* __restrict__ dis, int E)
{
    int e = blockIdx.x * 256 + threadIdx.x;
    if (e >= E) return;
    out[e] = out[e] * dis[row[e]] * dis[col[e]];
}

extern "C" void kernel_launch(void* const* d_in, const int* in_sizes, int n_in,
                              void* d_out, int out_size, void* d_ws, size_t ws_size,
                              hipStream_t stream) {
    const float* x      = (const float*)d_in[0];
    const float* W_nb   = (const float*)d_in[1];
    const float* b_nb   = (const float*)d_in[2];
    const float* W_self = (const float*)d_in[3];
    const float* b_self = (const float*)d_in[4];
    const float* W_att  = (const float*)d_in[5];
    const float* b_att  = (const float*)d_in[6];
    const float* values = (const float*)d_in[7];
    const float* noise  = (const float*)d_in[8];
    const int*   row    = (const int*)d_in[9];
    const int*   col    = (const int*)d_in[10];

    const int N = in_sizes[0] / D_DIM;
    const int E = in_sizes[7];
    float* out = (float*)d_out;

    char* ws = (char*)d_ws;
    ushort*   Wt     = (ushort*)ws;                     // 131072 B
    float*    g_nb   = (float*)(ws + 131072);           // N
    float*    g_self = g_nb + N;                        // N
    float*    dis    = g_self + N;                      // N
    unsigned* cnt    = (unsigned*)(dis + N);            // NBINS
    unsigned* bstart = cnt + NBINS;                     // NBINS+1
    unsigned* gcur   = bstart + NBINS + 1;              // NBINS
    // 8B-align spill
    size_t hdr = 131072 + (size_t)3 * N * 4 + (size_t)(3 * NBINS + 1) * 4;
    hdr = (hdr + 7) & ~(size_t)7;
    uint2*    spill  = (uint2*)(ws + hdr);              // E records

    int init_n = 2 * H_DIM * D_DIM;
    k0_init<<<(init_n + 255) / 256, 256, 0, stream>>>(W_nb, W_self, Wt, cnt);

    const int ntiles = (N + 63) / 64;
    k1_gemm<<<256, 512, 0, stream>>>(x, Wt, b_nb, b_self, W_att, g_nb, g_self, N, ntiles);

    p1_count<<<256, 256, 0, stream>>>(row, cnt, E);
    p2_scan<<<1, 64, 0, stream>>>(cnt, bstart, gcur);

    const int nt2 = (E + TILE - 1) / TILE;
    k2s_gate_sort<<<nt2, 1024, 0, stream>>>(row, col, values, noise, g_nb, g_self,
                                            b_att, out, spill, gcur, E);
    k2r_reduce<<<NBINS, 1024, 0, stream>>>(spill, bstart, gcur, dis, N);

    k3_edge2<<<(E + 255) / 256, 256, 0, stream>>>(row, col, out, dis, E);
}

// Round 13
// 71.568 us; speedup vs baseline: 1.1725x; 1.1725x over previous
//
#include <hip/hip_runtime.h>
#include <hip/hip_bf16.h>

typedef __attribute__((ext_vector_type(8))) short bf16x8;
typedef __attribute__((ext_vector_type(4))) float f32x4;

#define D_DIM 256   // input feature dim
#define H_DIM 128   // hidden dim per branch
#define NXCD 8      // XCDs on MI355X

// RNE float->bf16 (bit pattern)
__device__ inline ushort f2bf(float f) {
    union { float f; unsigned u; } a; a.f = f;
    unsigned r = a.u + 0x7fffu + ((a.u >> 16) & 1u);
    return (ushort)(r >> 16);
}

// K0: build Wt in FRAGMENT-MAJOR layout + zero the 8 per-XCD accumulator copies.
// Layout: Wt[((cg*4+ni)*8+ks)*512 + lane*8 + j] = W_branch[k][h]
//   with branch=cg>>1, h=(cg&1)*64+ni*16+(lane&15), k=ks*32+(lane>>4)*8+j.
// k1's Bf load then reads 64 lanes x contiguous 16B = fully coalesced.
__global__ void k0_init(const float* __restrict__ W_nb, const float* __restrict__ W_self,
                        ushort* __restrict__ Wt, float* __restrict__ priv, int PN) {
    int i = blockIdx.x * 256 + threadIdx.x;
    if (i < 2 * H_DIM * D_DIM) {
        int j    = i & 7;
        int lane = (i >> 3) & 63;
        int ks   = (i >> 9) & 7;
        int ni   = (i >> 12) & 3;
        int cg   = i >> 14;          // 0..3
        int li   = lane & 15;
        int grp  = lane >> 4;
        int h    = (cg & 1) * 64 + ni * 16 + li;
        int k    = ks * 32 + grp * 8 + j;
        const float* W = (cg >> 1) ? W_self : W_nb;
        Wt[i] = f2bf(W[k * H_DIM + h]);
    }
    if (i < PN) priv[i] = 0.f;
}

// K1: persistent-B fused GEMM (R6/R10 structure; Bf load now coalesced).
__global__ __launch_bounds__(512, 2) void k1_gemm(
    const float* __restrict__ x, const ushort* __restrict__ Wt,
    const float* __restrict__ b_nb, const float* __restrict__ b_self,
    const float* __restrict__ W_att,
    float* __restrict__ g_nb, float* __restrict__ g_self, int N, int ntiles)
{
    __shared__ __align__(16) ushort A_lds[64][264];
    __shared__ float part[2][2][64];

    const int t    = threadIdx.x;
    const int lane = t & 63;
    const int w    = t >> 6;
    const int rh   = w >> 2;
    const int cg   = w & 3;
    const int br   = cg >> 1;
    const int ch   = cg & 1;
    const int li   = lane & 15;
    const int grp  = lane >> 4;

    float bias[4], aw[4];
    #pragma unroll
    for (int ni = 0; ni < 4; ni++) {
        int hh = ch * 64 + ni * 16 + li;
        bias[ni] = br ? b_self[hh] : b_nb[hh];
        aw[ni]   = W_att[br * H_DIM + hh];
    }

    // persistent B fragments — coalesced: 64 lanes x contiguous 16B per load
    bf16x8 Bf[4][8];
    #pragma unroll
    for (int ni = 0; ni < 4; ni++)
        #pragma unroll
        for (int ks = 0; ks < 8; ks++)
            Bf[ni][ks] = *reinterpret_cast<const bf16x8*>(
                Wt + (((size_t)(cg * 4 + ni) * 8 + ks) << 9) + lane * 8);

    const int sr = t >> 3;
    const int sc = t & 7;

    for (int rt = blockIdx.x; rt < ntiles; rt += gridDim.x) {
        const int row0 = rt * 64;

        __syncthreads();
        {
            const int gr = row0 + sr;
            const bool v = gr < N;
            const float4* src = reinterpret_cast<const float4*>(x + (size_t)gr * D_DIM);
            #pragma unroll
            for (int j = 0; j < 8; j++) {
                int c4 = sc + j * 8;
                ushort4 o;
                if (v) {
                    float4 f = src[c4];
                    o.x = f2bf(f.x); o.y = f2bf(f.y); o.z = f2bf(f.z); o.w = f2bf(f.w);
                } else { o.x = 0; o.y = 0; o.z = 0; o.w = 0; }
                *reinterpret_cast<ushort4*>(&A_lds[sr][c4 * 4]) = o;
            }
        }
        __syncthreads();

        f32x4 acc[2][4];
        #pragma unroll
        for (int mi = 0; mi < 2; mi++)
            #pragma unroll
            for (int ni = 0; ni < 4; ni++) acc[mi][ni] = f32x4{0.f, 0.f, 0.f, 0.f};

        #pragma unroll
        for (int ks = 0; ks < 8; ks++) {
            bf16x8 af0 = *reinterpret_cast<const bf16x8*>(&A_lds[rh * 32 + li][ks * 32 + grp * 8]);
            bf16x8 af1 = *reinterpret_cast<const bf16x8*>(&A_lds[rh * 32 + 16 + li][ks * 32 + grp * 8]);
            #pragma unroll
            for (int ni = 0; ni < 4; ni++) {
                acc[0][ni] = __builtin_amdgcn_mfma_f32_16x16x32_bf16(af0, Bf[ni][ks], acc[0][ni], 0, 0, 0);
                acc[1][ni] = __builtin_amdgcn_mfma_f32_16x16x32_bf16(af1, Bf[ni][ks], acc[1][ni], 0, 0, 0);
            }
        }

        float p[2][4];
        #pragma unroll
        for (int mi = 0; mi < 2; mi++)
            #pragma unroll
            for (int r4 = 0; r4 < 4; r4++) p[mi][r4] = 0.f;
        #pragma unroll
        for (int ni = 0; ni < 4; ni++)
            #pragma unroll
            for (int mi = 0; mi < 2; mi++)
                #pragma unroll
                for (int r4 = 0; r4 < 4; r4++) {
                    float y = acc[mi][ni][r4] + bias[ni];
                    y = y > 0.f ? y : 0.f;
                    p[mi][r4] += y * aw[ni];
                }
        #pragma unroll
        for (int mi = 0; mi < 2; mi++)
            #pragma unroll
            for (int r4 = 0; r4 < 4; r4++) {
                float v = p[mi][r4];
                #pragma unroll
                for (int m = 1; m < 16; m <<= 1) v += __shfl_xor(v, m);
                if (li == 0)
                    part[br][ch][rh * 32 + mi * 16 + grp * 4 + r4] = v;
            }
        __syncthreads();

        if (t < 128) {
            int b_ = t >> 6, lr = t & 63;
            int gr = row0 + lr;
            if (gr < N) {
                float val = part[b_][0][lr] + part[b_][1][lr];
                if (b_) g_self[gr] = val; else g_nb[gr] = val;
            }
        }
    }
}

// K2: edge pass — gate/mask -> out; rowsum via workgroup-scope atomic into the
// calling XCD's private copy (selected by HW XCC_ID). (R10 form — best so far.)
__global__ __launch_bounds__(256) void k2_edge1(
    const int* __restrict__ row, const int* __restrict__ col,
    const float* __restrict__ values, const float* __restrict__ noise,
    const float* __restrict__ g_nb, const float* __restrict__ g_self,
    const float* __restrict__ b_att,
    float* __restrict__ mv_out, float* __restrict__ priv, int N, int E)
{
    unsigned xcd;
    asm volatile("s_getreg_b32 %0, hwreg(HW_REG_XCC_ID)" : "=s"(xcd));
    float* myp = priv + (size_t)(xcd & (NXCD - 1)) * N;

    int e = blockIdx.x * 256 + threadIdx.x;
    if (e >= E) return;
    int   r = row[e], c = col[e];
    float v = values[e];
    float u = noise[e] + 1e-7f;
    float la = g_nb[r] + g_self[c] + b_att[0];
    float gate = u / (u + (1.f - u) * __expf(-la));
    float mask = fminf(fmaxf(gate * 1.6f - 0.5f, 0.f), 1.f);
    float m = v * mask;
    mv_out[e] = m;
    if (m != 0.f)
        __hip_atomic_fetch_add(myp + r, m, __ATOMIC_RELAXED, __HIP_MEMORY_SCOPE_WORKGROUP);
}

// K2b: dis[n] = rsqrt(1e-10 + sum over the 8 XCD copies).
__global__ __launch_bounds__(256) void k2b_reduce(
    const float* __restrict__ priv, float* __restrict__ dis, int N)
{
    int n = blockIdx.x * 256 + threadIdx.x;
    if (n >= N) return;
    float s = 1e-10f;
    #pragma unroll
    for (int p = 0; p < NXCD; p++) s += priv[(size_t)p * N + n];
    dis[n] = rsqrtf(s);
}

// K3: symmetric degree normalization, gathers precomputed dis. (R10 form.)
__global__ __launch_bounds__(256) void k3_edge2(
    const int* __restrict__ row, const int* __restrict__ col,
    float* __restrict__ out, const float* __restrict__ dis, int E)
{
    int e = blockIdx.x * 256 + threadIdx.x;
    if (e >= E) return;
    out[e] = out[e] * dis[row[e]] * dis[col[e]];
}

extern "C" void kernel_launch(void* const* d_in, const int* in_sizes, int n_in,
                              void* d_out, int out_size, void* d_ws, size_t ws_size,
                              hipStream_t stream) {
    const float* x      = (const float*)d_in[0];
    const float* W_nb   = (const float*)d_in[1];
    const float* b_nb   = (const float*)d_in[2];
    const float* W_self = (const float*)d_in[3];
    const float* b_self = (const float*)d_in[4];
    const float* W_att  = (const float*)d_in[5];
    const float* b_att  = (const float*)d_in[6];
    const float* values = (const float*)d_in[7];
    const float* noise  = (const float*)d_in[8];
    const int*   row    = (const int*)d_in[9];
    const int*   col    = (const int*)d_in[10];

    const int N = in_sizes[0] / D_DIM;
    const int E = in_sizes[7];
    float* out = (float*)d_out;

    char* ws = (char*)d_ws;
    ushort* Wt     = (ushort*)ws;                       // 131072 B
    float*  g_nb   = (float*)(ws + 131072);             // N
    float*  g_self = g_nb + N;                          // N
    float*  dis    = g_self + N;                        // N
    float*  priv   = dis + N;                           // NXCD * N

    const int PN = NXCD * N;

    int init_n = 2 * H_DIM * D_DIM;
    if (PN > init_n) init_n = PN;
    k0_init<<<(init_n + 255) / 256, 256, 0, stream>>>(W_nb, W_self, Wt, priv, PN);

    const int ntiles = (N + 63) / 64;
    k1_gemm<<<256, 512, 0, stream>>>(x, Wt, b_nb, b_self, W_att, g_nb, g_self, N, ntiles);

    int eb1 = (E + 255) / 256;
    k2_edge1<<<eb1, 256, 0, stream>>>(row, col, values, noise, g_nb, g_self, b_att,
                                      out, priv, N, E);
    k2b_reduce<<<(N + 255) / 256, 256, 0, stream>>>(priv, dis, N);
    k3_edge2<<<eb1, 256, 0, stream>>>(row, col, out, dis, E);
}

// Round 14
// 68.435 us; speedup vs baseline: 1.2262x; 1.0458x over previous
//
#include <hip/hip_runtime.h>
#include <hip/hip_bf16.h>

typedef __attribute__((ext_vector_type(8))) short bf16x8;
typedef __attribute__((ext_vector_type(4))) float f32x4;

#define D_DIM 256   // input feature dim
#define H_DIM 128   // hidden dim per branch
#define QSH 12544   // rows per quarter (covers N <= 50176), 50176 B LDS
#define NSL 128     // edge slices

// RNE float->bf16 (bit pattern)
__device__ inline ushort f2bf(float f) {
    union { float f; unsigned u; } a; a.f = f;
    unsigned r = a.u + 0x7fffu + ((a.u >> 16) & 1u);
    return (ushort)(r >> 16);
}

// K0: build Wt in FRAGMENT-MAJOR layout (R13). Optionally init dis for fallback.
__global__ void k0_init(const float* __restrict__ W_nb, const float* __restrict__ W_self,
                        ushort* __restrict__ Wt, float* __restrict__ dis, int N, int init_dis) {
    int i = blockIdx.x * 256 + threadIdx.x;
    if (i < 2 * H_DIM * D_DIM) {
        int j    = i & 7;
        int lane = (i >> 3) & 63;
        int ks   = (i >> 9) & 7;
        int ni   = (i >> 12) & 3;
        int cg   = i >> 14;          // 0..3
        int li   = lane & 15;
        int grp  = lane >> 4;
        int h    = (cg & 1) * 64 + ni * 16 + li;
        int k    = ks * 32 + grp * 8 + j;
        const float* W = (cg >> 1) ? W_self : W_nb;
        Wt[i] = f2bf(W[k * H_DIM + h]);
    }
    if (init_dis && i < N) dis[i] = 1e-10f;
}

// K1: persistent-B fused GEMM (R13 form — coalesced frag-major Bf load).
__global__ __launch_bounds__(512, 2) void k1_gemm(
    const float* __restrict__ x, const ushort* __restrict__ Wt,
    const float* __restrict__ b_nb, const float* __restrict__ b_self,
    const float* __restrict__ W_att,
    float* __restrict__ g_nb, float* __restrict__ g_self, int N, int ntiles)
{
    __shared__ __align__(16) ushort A_lds[64][264];
    __shared__ float part[2][2][64];

    const int t    = threadIdx.x;
    const int lane = t & 63;
    const int w    = t >> 6;
    const int rh   = w >> 2;
    const int cg   = w & 3;
    const int br   = cg >> 1;
    const int ch   = cg & 1;
    const int li   = lane & 15;
    const int grp  = lane >> 4;

    float bias[4], aw[4];
    #pragma unroll
    for (int ni = 0; ni < 4; ni++) {
        int hh = ch * 64 + ni * 16 + li;
        bias[ni] = br ? b_self[hh] : b_nb[hh];
        aw[ni]   = W_att[br * H_DIM + hh];
    }

    bf16x8 Bf[4][8];
    #pragma unroll
    for (int ni = 0; ni < 4; ni++)
        #pragma unroll
        for (int ks = 0; ks < 8; ks++)
            Bf[ni][ks] = *reinterpret_cast<const bf16x8*>(
                Wt + (((size_t)(cg * 4 + ni) * 8 + ks) << 9) + lane * 8);

    const int sr = t >> 3;
    const int sc = t & 7;

    for (int rt = blockIdx.x; rt < ntiles; rt += gridDim.x) {
        const int row0 = rt * 64;

        __syncthreads();
        {
            const int gr = row0 + sr;
            const bool v = gr < N;
            const float4* src = reinterpret_cast<const float4*>(x + (size_t)gr * D_DIM);
            #pragma unroll
            for (int j = 0; j < 8; j++) {
                int c4 = sc + j * 8;
                ushort4 o;
                if (v) {
                    float4 f = src[c4];
                    o.x = f2bf(f.x); o.y = f2bf(f.y); o.z = f2bf(f.z); o.w = f2bf(f.w);
                } else { o.x = 0; o.y = 0; o.z = 0; o.w = 0; }
                *reinterpret_cast<ushort4*>(&A_lds[sr][c4 * 4]) = o;
            }
        }
        __syncthreads();

        f32x4 acc[2][4];
        #pragma unroll
        for (int mi = 0; mi < 2; mi++)
            #pragma unroll
            for (int ni = 0; ni < 4; ni++) acc[mi][ni] = f32x4{0.f, 0.f, 0.f, 0.f};

        #pragma unroll
        for (int ks = 0; ks < 8; ks++) {
            bf16x8 af0 = *reinterpret_cast<const bf16x8*>(&A_lds[rh * 32 + li][ks * 32 + grp * 8]);
            bf16x8 af1 = *reinterpret_cast<const bf16x8*>(&A_lds[rh * 32 + 16 + li][ks * 32 + grp * 8]);
            #pragma unroll
            for (int ni = 0; ni < 4; ni++) {
                acc[0][ni] = __builtin_amdgcn_mfma_f32_16x16x32_bf16(af0, Bf[ni][ks], acc[0][ni], 0, 0, 0);
                acc[1][ni] = __builtin_amdgcn_mfma_f32_16x16x32_bf16(af1, Bf[ni][ks], acc[1][ni], 0, 0, 0);
            }
        }

        float p[2][4];
        #pragma unroll
        for (int mi = 0; mi < 2; mi++)
            #pragma unroll
            for (int r4 = 0; r4 < 4; r4++) p[mi][r4] = 0.f;
        #pragma unroll
        for (int ni = 0; ni < 4; ni++)
            #pragma unroll
            for (int mi = 0; mi < 2; mi++)
                #pragma unroll
                for (int r4 = 0; r4 < 4; r4++) {
                    float y = acc[mi][ni][r4] + bias[ni];
                    y = y > 0.f ? y : 0.f;
                    p[mi][r4] += y * aw[ni];
                }
        #pragma unroll
        for (int mi = 0; mi < 2; mi++)
            #pragma unroll
            for (int r4 = 0; r4 < 4; r4++) {
                float v = p[mi][r4];
                #pragma unroll
                for (int m = 1; m < 16; m <<= 1) v += __shfl_xor(v, m);
                if (li == 0)
                    part[br][ch][rh * 32 + mi * 16 + grp * 4 + r4] = v;
            }
        __syncthreads();

        if (t < 128) {
            int b_ = t >> 6, lr = t & 63;
            int gr = row0 + lr;
            if (gr < N) {
                float val = part[b_][0][lr] + part[b_][1][lr];
                if (b_) g_self[gr] = val; else g_nb[gr] = val;
            }
        }
    }
}

// K2A: gate+mask -> out (=mv). 4 edges/thread, vectorized, no atomics.
__global__ __launch_bounds__(256) void k2a_gate(
    const int* __restrict__ row, const int* __restrict__ col,
    const float* __restrict__ values, const float* __restrict__ noise,
    const float* __restrict__ g_nb, const float* __restrict__ g_self,
    const float* __restrict__ b_att, float* __restrict__ mv_out, int E)
{
    int i = (blockIdx.x * 256 + threadIdx.x) * 4;
    if (i >= E) return;
    const float ba = b_att[0];
    if (i + 3 < E) {
        int4   r4 = *reinterpret_cast<const int4*>(row + i);
        int4   c4 = *reinterpret_cast<const int4*>(col + i);
        float4 v4 = *reinterpret_cast<const float4*>(values + i);
        float4 u4 = *reinterpret_cast<const float4*>(noise + i);
        int   rr[4] = { r4.x, r4.y, r4.z, r4.w };
        int   cc[4] = { c4.x, c4.y, c4.z, c4.w };
        float vv[4] = { v4.x, v4.y, v4.z, v4.w };
        float uu[4] = { u4.x, u4.y, u4.z, u4.w };
        float gn[4], gs[4];
        #pragma unroll
        for (int j = 0; j < 4; j++) { gn[j] = g_nb[rr[j]]; gs[j] = g_self[cc[j]]; }
        float m[4];
        #pragma unroll
        for (int j = 0; j < 4; j++) {
            float u    = uu[j] + 1e-7f;
            float la   = gn[j] + gs[j] + ba;
            float gate = u / (u + (1.f - u) * __expf(-la));
            float mask = fminf(fmaxf(gate * 1.6f - 0.5f, 0.f), 1.f);
            m[j] = vv[j] * mask;
        }
        *reinterpret_cast<float4*>(mv_out + i) = make_float4(m[0], m[1], m[2], m[3]);
    } else {
        for (int j = 0; j < 4 && i + j < E; j++) {
            int e = i + j;
            float u    = noise[e] + 1e-7f;
            float la   = g_nb[row[e]] + g_self[col[e]] + ba;
            float gate = u / (u + (1.f - u) * __expf(-la));
            float mask = fminf(fmaxf(gate * 1.6f - 0.5f, 0.f), 1.f);
            mv_out[e] = values[e] * mask;
        }
    }
}

// K2Q: quartered LDS rowsum scatter. 512 blocks x 1024 thr, 50KB LDS each
// (2 blocks/CU, 32 waves/CU, all 256 CUs). Block (s=bid>>2, q=bid&3) streams
// slice s (coalesced int4/float4), ds_add_f32 rows in [q*QSH,(q+1)*QSH),
// flushes f32 partials coalesced to priv[s]. Zero global atomics.
__global__ __launch_bounds__(1024) void k2q_scatter(
    const int* __restrict__ row, const float* __restrict__ mv,
    float* __restrict__ priv, int E, int ES)
{
    __shared__ float acc[QSH];
    const int s  = blockIdx.x >> 2;
    const int q  = blockIdx.x & 3;
    const int t  = threadIdx.x;
    const int lo = q * QSH;

    for (int i = t; i < QSH; i += 1024) acc[i] = 0.f;
    __syncthreads();

    const int base = s * ES;            // ES multiple of 4 -> 16B aligned
    int end = base + ES; if (end > E) end = E;

    int i = base + t * 4;
    for (; i + 3 < end; i += 4096) {
        int4   r4 = *reinterpret_cast<const int4*>(row + i);
        float4 m4 = *reinterpret_cast<const float4*>(mv + i);
        int d;
        d = r4.x - lo; if ((unsigned)d < (unsigned)QSH && m4.x != 0.f) atomicAdd(&acc[d], m4.x);
        d = r4.y - lo; if ((unsigned)d < (unsigned)QSH && m4.y != 0.f) atomicAdd(&acc[d], m4.y);
        d = r4.z - lo; if ((unsigned)d < (unsigned)QSH && m4.z != 0.f) atomicAdd(&acc[d], m4.z);
        d = r4.w - lo; if ((unsigned)d < (unsigned)QSH && m4.w != 0.f) atomicAdd(&acc[d], m4.w);
    }
    for (; i < end; i++) {              // scalar tail
        int d = row[i] - lo;
        float m = mv[i];
        if ((unsigned)d < (unsigned)QSH && m != 0.f) atomicAdd(&acc[d], m);
    }
    __syncthreads();

    float* dst = priv + (size_t)s * (4 * QSH) + lo;
    for (int j = t; j < QSH; j += 1024) dst[j] = acc[j];
}

// K2C: dis[n] = rsqrt(1e-10 + sum over NSL slice partials). Coalesced.
__global__ __launch_bounds__(256) void k2c_reduce(
    const float* __restrict__ priv, float* __restrict__ dis, int N)
{
    int n = blockIdx.x * 256 + threadIdx.x;
    if (n >= N) return;
    float s = 1e-10f;
    for (int p = 0; p < NSL; p++) s += priv[(size_t)p * (4 * QSH) + n];
    dis[n] = rsqrtf(s);
}

// Fallback (N > 4*QSH): fused gate + device atomic into dis (R3-style).
__global__ __launch_bounds__(256) void k2_atomic_fb(
    const int* __restrict__ row, const int* __restrict__ col,
    const float* __restrict__ values, const float* __restrict__ noise,
    const float* __restrict__ g_nb, const float* __restrict__ g_self,
    const float* __restrict__ b_att,
    float* __restrict__ out, float* __restrict__ dis, int E)
{
    int e = blockIdx.x * 256 + threadIdx.x;
    if (e >= E) return;
    int   r = row[e], c = col[e];
    float u = noise[e] + 1e-7f;
    float la = g_nb[r] + g_self[c] + b_att[0];
    float gate = u / (u + (1.f - u) * __expf(-la));
    float mask = fminf(fmaxf(gate * 1.6f - 0.5f, 0.f), 1.f);
    float m = values[e] * mask;
    out[e] = m;
    if (m != 0.f) atomicAdd(&dis[r], m);
}
__global__ __launch_bounds__(256) void k2c_rsqrt_fb(float* __restrict__ dis, int N)
{
    int n = blockIdx.x * 256 + threadIdx.x;
    if (n < N) dis[n] = rsqrtf(dis[n]);
}

// K3: symmetric degree normalization, gathers precomputed dis.
__global__ __launch_bounds__(256) void k3_edge2(
    const int* __restrict__ row, const int* __restrict__ col,
    float* __restrict__ out, const float* __restrict__ dis, int E)
{
    int e = blockIdx.x * 256 + threadIdx.x;
    if (e >= E) return;
    out[e] = out[e] * dis[row[e]] * dis[col[e]];
}

extern "C" void kernel_launch(void* const* d_in, const int* in_sizes, int n_in,
                              void* d_out, int out_size, void* d_ws, size_t ws_size,
                              hipStream_t stream) {
    const float* x      = (const float*)d_in[0];
    const float* W_nb   = (const float*)d_in[1];
    const float* b_nb   = (const float*)d_in[2];
    const float* W_self = (const float*)d_in[3];
    const float* b_self = (const float*)d_in[4];
    const float* W_att  = (const float*)d_in[5];
    const float* b_att  = (const float*)d_in[6];
    const float* values = (const float*)d_in[7];
    const float* noise  = (const float*)d_in[8];
    const int*   row    = (const int*)d_in[9];
    const int*   col    = (const int*)d_in[10];

    const int N = in_sizes[0] / D_DIM;
    const int E = in_sizes[7];
    float* out = (float*)d_out;

    char* ws = (char*)d_ws;
    ushort* Wt     = (ushort*)ws;                       // 131072 B
    float*  g_nb   = (float*)(ws + 131072);             // N
    float*  g_self = g_nb + N;                          // N
    float*  dis    = g_self + N;                        // N
    float*  priv   = dis + N;                           // NSL * 4*QSH f32 (~25.7MB)

    // ES: edges per slice, multiple of 4 for int4/float4 alignment
    int ES = ((E + NSL - 1) / NSL + 3) & ~3;
    size_t need = 131072 + (size_t)3 * N * 4 + (size_t)NSL * 4 * QSH * 4;
    bool lds_path = (N <= 4 * QSH) && (need <= ws_size);

    int init_n = 2 * H_DIM * D_DIM;
    if (N > init_n) init_n = N;
    k0_init<<<(init_n + 255) / 256, 256, 0, stream>>>(W_nb, W_self, Wt, dis, N, lds_path ? 0 : 1);

    const int ntiles = (N + 63) / 64;
    k1_gemm<<<256, 512, 0, stream>>>(x, Wt, b_nb, b_self, W_att, g_nb, g_self, N, ntiles);

    if (lds_path) {
        int eb4 = ((E + 3) / 4 + 255) / 256;
        k2a_gate<<<eb4, 256, 0, stream>>>(row, col, values, noise, g_nb, g_self, b_att, out, E);
        k2q_scatter<<<NSL * 4, 1024, 0, stream>>>(row, out, priv, E, ES);
        k2c_reduce<<<(N + 255) / 256, 256, 0, stream>>>(priv, dis, N);
    } else {
        k2_atomic_fb<<<(E + 255) / 256, 256, 0, stream>>>(row, col, values, noise,
                                                          g_nb, g_self, b_att, out, dis, E);
        k2c_rsqrt_fb<<<(N + 255) / 256, 256, 0, stream>>>(dis, N);
    }

    k3_edge2<<<(E + 255) / 256, 256, 0, stream>>>(row, col, out, dis, E);
}

// Round 15
// 66.932 us; speedup vs baseline: 1.2537x; 1.0224x over previous
//
#include <hip/hip_runtime.h>
#include <hip/hip_bf16.h>

typedef __attribute__((ext_vector_type(8))) short bf16x8;
typedef __attribute__((ext_vector_type(4))) float f32x4;

#define D_DIM 256   // input feature dim
#define H_DIM 128   // hidden dim per branch
#define QSH 12544   // rows per quarter (covers N <= 50176), 50176 B LDS
#define NSL 128     // edge slices

// RNE float->bf16 (bit pattern)
__device__ inline ushort f2bf(float f) {
    union { float f; unsigned u; } a; a.f = f;
    unsigned r = a.u + 0x7fffu + ((a.u >> 16) & 1u);
    return (ushort)(r >> 16);
}
__device__ inline float bf2f(unsigned hi16) {
    union { unsigned u; float f; } a; a.u = hi16 << 16;
    return a.f;
}

// K0: build Wt in FRAGMENT-MAJOR layout (R13). Optionally init dis for fallback.
__global__ void k0_init(const float* __restrict__ W_nb, const float* __restrict__ W_self,
                        ushort* __restrict__ Wt, float* __restrict__ dis, int N, int init_dis) {
    int i = blockIdx.x * 256 + threadIdx.x;
    if (i < 2 * H_DIM * D_DIM) {
        int j    = i & 7;
        int lane = (i >> 3) & 63;
        int ks   = (i >> 9) & 7;
        int ni   = (i >> 12) & 3;
        int cg   = i >> 14;          // 0..3
        int li   = lane & 15;
        int grp  = lane >> 4;
        int h    = (cg & 1) * 64 + ni * 16 + li;
        int k    = ks * 32 + grp * 8 + j;
        const float* W = (cg >> 1) ? W_self : W_nb;
        Wt[i] = f2bf(W[k * H_DIM + h]);
    }
    if (init_dis && i < N) dis[i] = 1e-10f;
}

// K1: persistent-B fused GEMM (R13 form — coalesced frag-major Bf load).
__global__ __launch_bounds__(512, 2) void k1_gemm(
    const float* __restrict__ x, const ushort* __restrict__ Wt,
    const float* __restrict__ b_nb, const float* __restrict__ b_self,
    const float* __restrict__ W_att,
    float* __restrict__ g_nb, float* __restrict__ g_self, int N, int ntiles)
{
    __shared__ __align__(16) ushort A_lds[64][264];
    __shared__ float part[2][2][64];

    const int t    = threadIdx.x;
    const int lane = t & 63;
    const int w    = t >> 6;
    const int rh   = w >> 2;
    const int cg   = w & 3;
    const int br   = cg >> 1;
    const int ch   = cg & 1;
    const int li   = lane & 15;
    const int grp  = lane >> 4;

    float bias[4], aw[4];
    #pragma unroll
    for (int ni = 0; ni < 4; ni++) {
        int hh = ch * 64 + ni * 16 + li;
        bias[ni] = br ? b_self[hh] : b_nb[hh];
        aw[ni]   = W_att[br * H_DIM + hh];
    }

    bf16x8 Bf[4][8];
    #pragma unroll
    for (int ni = 0; ni < 4; ni++)
        #pragma unroll
        for (int ks = 0; ks < 8; ks++)
            Bf[ni][ks] = *reinterpret_cast<const bf16x8*>(
                Wt + (((size_t)(cg * 4 + ni) * 8 + ks) << 9) + lane * 8);

    const int sr = t >> 3;
    const int sc = t & 7;

    for (int rt = blockIdx.x; rt < ntiles; rt += gridDim.x) {
        const int row0 = rt * 64;

        __syncthreads();
        {
            const int gr = row0 + sr;
            const bool v = gr < N;
            const float4* src = reinterpret_cast<const float4*>(x + (size_t)gr * D_DIM);
            #pragma unroll
            for (int j = 0; j < 8; j++) {
                int c4 = sc + j * 8;
                ushort4 o;
                if (v) {
                    float4 f = src[c4];
                    o.x = f2bf(f.x); o.y = f2bf(f.y); o.z = f2bf(f.z); o.w = f2bf(f.w);
                } else { o.x = 0; o.y = 0; o.z = 0; o.w = 0; }
                *reinterpret_cast<ushort4*>(&A_lds[sr][c4 * 4]) = o;
            }
        }
        __syncthreads();

        f32x4 acc[2][4];
        #pragma unroll
        for (int mi = 0; mi < 2; mi++)
            #pragma unroll
            for (int ni = 0; ni < 4; ni++) acc[mi][ni] = f32x4{0.f, 0.f, 0.f, 0.f};

        #pragma unroll
        for (int ks = 0; ks < 8; ks++) {
            bf16x8 af0 = *reinterpret_cast<const bf16x8*>(&A_lds[rh * 32 + li][ks * 32 + grp * 8]);
            bf16x8 af1 = *reinterpret_cast<const bf16x8*>(&A_lds[rh * 32 + 16 + li][ks * 32 + grp * 8]);
            #pragma unroll
            for (int ni = 0; ni < 4; ni++) {
                acc[0][ni] = __builtin_amdgcn_mfma_f32_16x16x32_bf16(af0, Bf[ni][ks], acc[0][ni], 0, 0, 0);
                acc[1][ni] = __builtin_amdgcn_mfma_f32_16x16x32_bf16(af1, Bf[ni][ks], acc[1][ni], 0, 0, 0);
            }
        }

        float p[2][4];
        #pragma unroll
        for (int mi = 0; mi < 2; mi++)
            #pragma unroll
            for (int r4 = 0; r4 < 4; r4++) p[mi][r4] = 0.f;
        #pragma unroll
        for (int ni = 0; ni < 4; ni++)
            #pragma unroll
            for (int mi = 0; mi < 2; mi++)
                #pragma unroll
                for (int r4 = 0; r4 < 4; r4++) {
                    float y = acc[mi][ni][r4] + bias[ni];
                    y = y > 0.f ? y : 0.f;
                    p[mi][r4] += y * aw[ni];
                }
        #pragma unroll
        for (int mi = 0; mi < 2; mi++)
            #pragma unroll
            for (int r4 = 0; r4 < 4; r4++) {
                float v = p[mi][r4];
                #pragma unroll
                for (int m = 1; m < 16; m <<= 1) v += __shfl_xor(v, m);
                if (li == 0)
                    part[br][ch][rh * 32 + mi * 16 + grp * 4 + r4] = v;
            }
        __syncthreads();

        if (t < 128) {
            int b_ = t >> 6, lr = t & 63;
            int gr = row0 + lr;
            if (gr < N) {
                float val = part[b_][0][lr] + part[b_][1][lr];
                if (b_) g_self[gr] = val; else g_nb[gr] = val;
            }
        }
    }
}

// K2A: gate+mask -> out (=mv). 4 edges/thread, vectorized, no atomics.
__global__ __launch_bounds__(256) void k2a_gate(
    const int* __restrict__ row, const int* __restrict__ col,
    const float* __restrict__ values, const float* __restrict__ noise,
    const float* __restrict__ g_nb, const float* __restrict__ g_self,
    const float* __restrict__ b_att, float* __restrict__ mv_out, int E)
{
    int i = (blockIdx.x * 256 + threadIdx.x) * 4;
    if (i >= E) return;
    const float ba = b_att[0];
    if (i + 3 < E) {
        int4   r4 = *reinterpret_cast<const int4*>(row + i);
        int4   c4 = *reinterpret_cast<const int4*>(col + i);
        float4 v4 = *reinterpret_cast<const float4*>(values + i);
        float4 u4 = *reinterpret_cast<const float4*>(noise + i);
        int   rr[4] = { r4.x, r4.y, r4.z, r4.w };
        int   cc[4] = { c4.x, c4.y, c4.z, c4.w };
        float vv[4] = { v4.x, v4.y, v4.z, v4.w };
        float uu[4] = { u4.x, u4.y, u4.z, u4.w };
        float gn[4], gs[4];
        #pragma unroll
        for (int j = 0; j < 4; j++) { gn[j] = g_nb[rr[j]]; gs[j] = g_self[cc[j]]; }
        float m[4];
        #pragma unroll
        for (int j = 0; j < 4; j++) {
            float u    = uu[j] + 1e-7f;
            float la   = gn[j] + gs[j] + ba;
            float gate = u / (u + (1.f - u) * __expf(-la));
            float mask = fminf(fmaxf(gate * 1.6f - 0.5f, 0.f), 1.f);
            m[j] = vv[j] * mask;
        }
        *reinterpret_cast<float4*>(mv_out + i) = make_float4(m[0], m[1], m[2], m[3]);
    } else {
        for (int j = 0; j < 4 && i + j < E; j++) {
            int e = i + j;
            float u    = noise[e] + 1e-7f;
            float la   = g_nb[row[e]] + g_self[col[e]] + ba;
            float gate = u / (u + (1.f - u) * __expf(-la));
            float mask = fminf(fmaxf(gate * 1.6f - 0.5f, 0.f), 1.f);
            mv_out[e] = values[e] * mask;
        }
    }
}

// K2Q: quartered LDS rowsum scatter (R14 structure), bf16 partial flush.
// 512 blocks x 1024 thr, 50KB LDS (2 blocks/CU, 32 waves/CU, all 256 CUs).
__global__ __launch_bounds__(1024) void k2q_scatter(
    const int* __restrict__ row, const float* __restrict__ mv,
    ushort* __restrict__ priv, int E, int ES)
{
    __shared__ float acc[QSH];
    const int s  = blockIdx.x >> 2;
    const int q  = blockIdx.x & 3;
    const int t  = threadIdx.x;
    const int lo = q * QSH;

    for (int i = t; i < QSH; i += 1024) acc[i] = 0.f;
    __syncthreads();

    const int base = s * ES;            // ES multiple of 4 -> 16B aligned
    int end = base + ES; if (end > E) end = E;

    int i = base + t * 4;
    for (; i + 3 < end; i += 4096) {
        int4   r4 = *reinterpret_cast<const int4*>(row + i);
        float4 m4 = *reinterpret_cast<const float4*>(mv + i);
        int d;
        d = r4.x - lo; if ((unsigned)d < (unsigned)QSH && m4.x != 0.f) atomicAdd(&acc[d], m4.x);
        d = r4.y - lo; if ((unsigned)d < (unsigned)QSH && m4.y != 0.f) atomicAdd(&acc[d], m4.y);
        d = r4.z - lo; if ((unsigned)d < (unsigned)QSH && m4.z != 0.f) atomicAdd(&acc[d], m4.z);
        d = r4.w - lo; if ((unsigned)d < (unsigned)QSH && m4.w != 0.f) atomicAdd(&acc[d], m4.w);
    }
    for (; i < end; i++) {              // scalar tail
        int d = row[i] - lo;
        float m = mv[i];
        if ((unsigned)d < (unsigned)QSH && m != 0.f) atomicAdd(&acc[d], m);
    }
    __syncthreads();

    // flush bf16 partials: 2 rows packed per uint, coalesced (QSH, lo both even)
    ushort* dst = priv + (size_t)s * (4 * QSH) + lo;
    for (int j = t * 2; j < QSH; j += 2048) {
        unsigned pk = (unsigned)f2bf(acc[j]) | ((unsigned)f2bf(acc[j + 1]) << 16);
        *reinterpret_cast<unsigned*>(dst + j) = pk;
    }
}

// K2C: dis[n] = rsqrt(1e-10 + sum over NSL bf16 slice partials). 2 rows/thread.
__global__ __launch_bounds__(256) void k2c_reduce(
    const ushort* __restrict__ priv, float* __restrict__ dis, int N)
{
    int n0 = (blockIdx.x * 256 + threadIdx.x) * 2;
    if (n0 >= N) return;
    float s0 = 1e-10f, s1 = 1e-10f;
    for (int p = 0; p < NSL; p++) {
        unsigned v = *reinterpret_cast<const unsigned*>(priv + (size_t)p * (4 * QSH) + n0);
        s0 += bf2f(v & 0xffffu);
        s1 += bf2f(v >> 16);
    }
    dis[n0] = rsqrtf(s0);
    if (n0 + 1 < N) dis[n0 + 1] = rsqrtf(s1);
}

// Fallback (N > 4*QSH): fused gate + device atomic into dis (R3-style).
__global__ __launch_bounds__(256) void k2_atomic_fb(
    const int* __restrict__ row, const int* __restrict__ col,
    const float* __restrict__ values, const float* __restrict__ noise,
    const float* __restrict__ g_nb, const float* __restrict__ g_self,
    const float* __restrict__ b_att,
    float* __restrict__ out, float* __restrict__ dis, int E)
{
    int e = blockIdx.x * 256 + threadIdx.x;
    if (e >= E) return;
    int   r = row[e], c = col[e];
    float u = noise[e] + 1e-7f;
    float la = g_nb[r] + g_self[c] + b_att[0];
    float gate = u / (u + (1.f - u) * __expf(-la));
    float mask = fminf(fmaxf(gate * 1.6f - 0.5f, 0.f), 1.f);
    float m = values[e] * mask;
    out[e] = m;
    if (m != 0.f) atomicAdd(&dis[r], m);
}
__global__ __launch_bounds__(256) void k2c_rsqrt_fb(float* __restrict__ dis, int N)
{
    int n = blockIdx.x * 256 + threadIdx.x;
    if (n < N) dis[n] = rsqrtf(dis[n]);
}

// K3: symmetric degree normalization — 4 edges/thread, 8 outstanding gathers.
__global__ __launch_bounds__(256) void k3_edge2(
    const int* __restrict__ row, const int* __restrict__ col,
    float* __restrict__ out, const float* __restrict__ dis, int E)
{
    int i = (blockIdx.x * 256 + threadIdx.x) * 4;
    if (i >= E) return;
    if (i + 3 < E) {
        int4   r4 = *reinterpret_cast<const int4*>(row + i);
        int4   c4 = *reinterpret_cast<const int4*>(col + i);
        float4 m4 = *reinterpret_cast<const float4*>(out + i);
        float dr0 = dis[r4.x], dc0 = dis[c4.x];
        float dr1 = dis[r4.y], dc1 = dis[c4.y];
        float dr2 = dis[r4.z], dc2 = dis[c4.z];
        float dr3 = dis[r4.w], dc3 = dis[c4.w];
        float4 o;
        o.x = m4.x * dr0 * dc0;
        o.y = m4.y * dr1 * dc1;
        o.z = m4.z * dr2 * dc2;
        o.w = m4.w * dr3 * dc3;
        *reinterpret_cast<float4*>(out + i) = o;
    } else {
        for (int j = 0; j < 4 && i + j < E; j++) {
            int e = i + j;
            out[e] = out[e] * dis[row[e]] * dis[col[e]];
        }
    }
}

extern "C" void kernel_launch(void* const* d_in, const int* in_sizes, int n_in,
                              void* d_out, int out_size, void* d_ws, size_t ws_size,
                              hipStream_t stream) {
    const float* x      = (const float*)d_in[0];
    const float* W_nb   = (const float*)d_in[1];
    const float* b_nb   = (const float*)d_in[2];
    const float* W_self = (const float*)d_in[3];
    const float* b_self = (const float*)d_in[4];
    const float* W_att  = (const float*)d_in[5];
    const float* b_att  = (const float*)d_in[6];
    const float* values = (const float*)d_in[7];
    const float* noise  = (const float*)d_in[8];
    const int*   row    = (const int*)d_in[9];
    const int*   col    = (const int*)d_in[10];

    const int N = in_sizes[0] / D_DIM;
    const int E = in_sizes[7];
    float* out = (float*)d_out;

    char* ws = (char*)d_ws;
    ushort* Wt     = (ushort*)ws;                       // 131072 B
    float*  g_nb   = (float*)(ws + 131072);             // N
    float*  g_self = g_nb + N;                          // N
    float*  dis    = g_self + N;                        // N
    ushort* priv   = (ushort*)(dis + N);                // NSL * 4*QSH bf16 (~12.8MB)

    // ES: edges per slice, multiple of 4 for int4/float4 alignment
    int ES = ((E + NSL - 1) / NSL + 3) & ~3;
    size_t need = 131072 + (size_t)3 * N * 4 + (size_t)NSL * 4 * QSH * 2;
    bool lds_path = (N <= 4 * QSH) && (need <= ws_size);

    int init_n = 2 * H_DIM * D_DIM;
    if (N > init_n) init_n = N;
    k0_init<<<(init_n + 255) / 256, 256, 0, stream>>>(W_nb, W_self, Wt, dis, N, lds_path ? 0 : 1);

    const int ntiles = (N + 63) / 64;
    k1_gemm<<<256, 512, 0, stream>>>(x, Wt, b_nb, b_self, W_att, g_nb, g_self, N, ntiles);

    int eb4 = ((E + 3) / 4 + 255) / 256;
    if (lds_path) {
        k2a_gate<<<eb4, 256, 0, stream>>>(row, col, values, noise, g_nb, g_self, b_att, out, E);
        k2q_scatter<<<NSL * 4, 1024, 0, stream>>>(row, out, priv, E, ES);
        k2c_reduce<<<((N + 1) / 2 + 255) / 256, 256, 0, stream>>>(priv, dis, N);
    } else {
        k2_atomic_fb<<<(E + 255) / 256, 256, 0, stream>>>(row, col, values, noise,
                                                          g_nb, g_self, b_att, out, dis, E);
        k2c_rsqrt_fb<<<(N + 255) / 256, 256, 0, stream>>>(dis, N);
    }

    k3_edge2<<<eb4, 256, 0, stream>>>(row, col, out, dis, E);
}

// Round 16
// 62.367 us; speedup vs baseline: 1.3455x; 1.0732x over previous
//
#include <hip/hip_runtime.h>
#include <hip/hip_bf16.h>

typedef __attribute__((ext_vector_type(8))) short bf16x8;
typedef __attribute__((ext_vector_type(4))) float f32x4;

#define D_DIM 256   // input feature dim
#define H_DIM 128   // hidden dim per branch
#define QSH 12544   // rows per quarter; LDS f32 acc = 50176 B
#define NSL 128     // edge slices
#define NMAXL (4 * QSH)   // max N for lds path (=> 100352 B bf16 dis LDS)

// RNE float->bf16 (bit pattern)
__device__ inline ushort f2bf(float f) {
    union { float f; unsigned u; } a; a.f = f;
    unsigned r = a.u + 0x7fffu + ((a.u >> 16) & 1u);
    return (ushort)(r >> 16);
}
__device__ inline float bf2f(unsigned hi16) {
    union { unsigned u; float f; } a; a.u = hi16 << 16;
    return a.f;
}

// K0: build Wt in FRAGMENT-MAJOR layout (R13). Optionally init dis for fallback.
__global__ void k0_init(const float* __restrict__ W_nb, const float* __restrict__ W_self,
                        ushort* __restrict__ Wt, float* __restrict__ dis, int N, int init_dis) {
    int i = blockIdx.x * 256 + threadIdx.x;
    if (i < 2 * H_DIM * D_DIM) {
        int j    = i & 7;
        int lane = (i >> 3) & 63;
        int ks   = (i >> 9) & 7;
        int ni   = (i >> 12) & 3;
        int cg   = i >> 14;          // 0..3
        int li   = lane & 15;
        int grp  = lane >> 4;
        int h    = (cg & 1) * 64 + ni * 16 + li;
        int k    = ks * 32 + grp * 8 + j;
        const float* W = (cg >> 1) ? W_self : W_nb;
        Wt[i] = f2bf(W[k * H_DIM + h]);
    }
    if (init_dis && i < N) dis[i] = 1e-10f;
}

// K1: persistent-B fused GEMM (R13 form — coalesced frag-major Bf load).
__global__ __launch_bounds__(512, 2) void k1_gemm(
    const float* __restrict__ x, const ushort* __restrict__ Wt,
    const float* __restrict__ b_nb, const float* __restrict__ b_self,
    const float* __restrict__ W_att,
    float* __restrict__ g_nb, float* __restrict__ g_self, int N, int ntiles)
{
    __shared__ __align__(16) ushort A_lds[64][264];
    __shared__ float part[2][2][64];

    const int t    = threadIdx.x;
    const int lane = t & 63;
    const int w    = t >> 6;
    const int rh   = w >> 2;
    const int cg   = w & 3;
    const int br   = cg >> 1;
    const int ch   = cg & 1;
    const int li   = lane & 15;
    const int grp  = lane >> 4;

    float bias[4], aw[4];
    #pragma unroll
    for (int ni = 0; ni < 4; ni++) {
        int hh = ch * 64 + ni * 16 + li;
        bias[ni] = br ? b_self[hh] : b_nb[hh];
        aw[ni]   = W_att[br * H_DIM + hh];
    }

    bf16x8 Bf[4][8];
    #pragma unroll
    for (int ni = 0; ni < 4; ni++)
        #pragma unroll
        for (int ks = 0; ks < 8; ks++)
            Bf[ni][ks] = *reinterpret_cast<const bf16x8*>(
                Wt + (((size_t)(cg * 4 + ni) * 8 + ks) << 9) + lane * 8);

    const int sr = t >> 3;
    const int sc = t & 7;

    for (int rt = blockIdx.x; rt < ntiles; rt += gridDim.x) {
        const int row0 = rt * 64;

        __syncthreads();
        {
            const int gr = row0 + sr;
            const bool v = gr < N;
            const float4* src = reinterpret_cast<const float4*>(x + (size_t)gr * D_DIM);
            #pragma unroll
            for (int j = 0; j < 8; j++) {
                int c4 = sc + j * 8;
                ushort4 o;
                if (v) {
                    float4 f = src[c4];
                    o.x = f2bf(f.x); o.y = f2bf(f.y); o.z = f2bf(f.z); o.w = f2bf(f.w);
                } else { o.x = 0; o.y = 0; o.z = 0; o.w = 0; }
                *reinterpret_cast<ushort4*>(&A_lds[sr][c4 * 4]) = o;
            }
        }
        __syncthreads();

        f32x4 acc[2][4];
        #pragma unroll
        for (int mi = 0; mi < 2; mi++)
            #pragma unroll
            for (int ni = 0; ni < 4; ni++) acc[mi][ni] = f32x4{0.f, 0.f, 0.f, 0.f};

        #pragma unroll
        for (int ks = 0; ks < 8; ks++) {
            bf16x8 af0 = *reinterpret_cast<const bf16x8*>(&A_lds[rh * 32 + li][ks * 32 + grp * 8]);
            bf16x8 af1 = *reinterpret_cast<const bf16x8*>(&A_lds[rh * 32 + 16 + li][ks * 32 + grp * 8]);
            #pragma unroll
            for (int ni = 0; ni < 4; ni++) {
                acc[0][ni] = __builtin_amdgcn_mfma_f32_16x16x32_bf16(af0, Bf[ni][ks], acc[0][ni], 0, 0, 0);
                acc[1][ni] = __builtin_amdgcn_mfma_f32_16x16x32_bf16(af1, Bf[ni][ks], acc[1][ni], 0, 0, 0);
            }
        }

        float p[2][4];
        #pragma unroll
        for (int mi = 0; mi < 2; mi++)
            #pragma unroll
            for (int r4 = 0; r4 < 4; r4++) p[mi][r4] = 0.f;
        #pragma unroll
        for (int ni = 0; ni < 4; ni++)
            #pragma unroll
            for (int mi = 0; mi < 2; mi++)
                #pragma unroll
                for (int r4 = 0; r4 < 4; r4++) {
                    float y = acc[mi][ni][r4] + bias[ni];
                    y = y > 0.f ? y : 0.f;
                    p[mi][r4] += y * aw[ni];
                }
        #pragma unroll
        for (int mi = 0; mi < 2; mi++)
            #pragma unroll
            for (int r4 = 0; r4 < 4; r4++) {
                float v = p[mi][r4];
                #pragma unroll
                for (int m = 1; m < 16; m <<= 1) v += __shfl_xor(v, m);
                if (li == 0)
                    part[br][ch][rh * 32 + mi * 16 + grp * 4 + r4] = v;
            }
        __syncthreads();

        if (t < 128) {
            int b_ = t >> 6, lr = t & 63;
            int gr = row0 + lr;
            if (gr < N) {
                float val = part[b_][0][lr] + part[b_][1][lr];
                if (b_) g_self[gr] = val; else g_nb[gr] = val;
            }
        }
    }
}

// K2A: gate+mask -> out (=mv, f32) AND packed sidecar pk = (row<<16)|bf16(mv).
// 4 edges/thread, vectorized, no atomics. (pk valid only when N <= 65536.)
__global__ __launch_bounds__(256) void k2a_gate(
    const int* __restrict__ row, const int* __restrict__ col,
    const float* __restrict__ values, const float* __restrict__ noise,
    const float* __restrict__ g_nb, const float* __restrict__ g_self,
    const float* __restrict__ b_att, float* __restrict__ mv_out,
    unsigned* __restrict__ pk, int E)
{
    int i = (blockIdx.x * 256 + threadIdx.x) * 4;
    if (i >= E) return;
    const float ba = b_att[0];
    if (i + 3 < E) {
        int4   r4 = *reinterpret_cast<const int4*>(row + i);
        int4   c4 = *reinterpret_cast<const int4*>(col + i);
        float4 v4 = *reinterpret_cast<const float4*>(values + i);
        float4 u4 = *reinterpret_cast<const float4*>(noise + i);
        int   rr[4] = { r4.x, r4.y, r4.z, r4.w };
        int   cc[4] = { c4.x, c4.y, c4.z, c4.w };
        float vv[4] = { v4.x, v4.y, v4.z, v4.w };
        float uu[4] = { u4.x, u4.y, u4.z, u4.w };
        float gn[4], gs[4];
        #pragma unroll
        for (int j = 0; j < 4; j++) { gn[j] = g_nb[rr[j]]; gs[j] = g_self[cc[j]]; }
        float m[4]; unsigned pkv[4];
        #pragma unroll
        for (int j = 0; j < 4; j++) {
            float u    = uu[j] + 1e-7f;
            float la   = gn[j] + gs[j] + ba;
            float gate = u / (u + (1.f - u) * __expf(-la));
            float mask = fminf(fmaxf(gate * 1.6f - 0.5f, 0.f), 1.f);
            m[j] = vv[j] * mask;
            pkv[j] = ((unsigned)rr[j] << 16) | (unsigned)f2bf(m[j]);
        }
        *reinterpret_cast<float4*>(mv_out + i) = make_float4(m[0], m[1], m[2], m[3]);
        *reinterpret_cast<uint4*>(pk + i) = make_uint4(pkv[0], pkv[1], pkv[2], pkv[3]);
    } else {
        for (int j = 0; j < 4 && i + j < E; j++) {
            int e = i + j;
            int   r = row[e];
            float u    = noise[e] + 1e-7f;
            float la   = g_nb[r] + g_self[col[e]] + ba;
            float gate = u / (u + (1.f - u) * __expf(-la));
            float mask = fminf(fmaxf(gate * 1.6f - 0.5f, 0.f), 1.f);
            float m = values[e] * mask;
            mv_out[e] = m;
            pk[e] = ((unsigned)r << 16) | (unsigned)f2bf(m);
        }
    }
}

// K2Q: quartered LDS rowsum scatter over the packed stream (half the read BW).
// 512 blocks x 1024 thr, 50KB LDS (2 blocks/CU, 32 waves/CU, all 256 CUs).
__global__ __launch_bounds__(1024) void k2q_scatter(
    const unsigned* __restrict__ pk, ushort* __restrict__ priv, int E, int ES)
{
    __shared__ float acc[QSH];
    const int s  = blockIdx.x >> 2;
    const int q  = blockIdx.x & 3;
    const int t  = threadIdx.x;
    const int lo = q * QSH;

    for (int i = t; i < QSH; i += 1024) acc[i] = 0.f;
    __syncthreads();

    const int base = s * ES;            // ES multiple of 4 -> 16B aligned
    int end = base + ES; if (end > E) end = E;

    int i = base + t * 4;
    for (; i + 3 < end; i += 4096) {
        uint4 p4 = *reinterpret_cast<const uint4*>(pk + i);
        unsigned p; int d; float m;
        p = p4.x; d = (int)(p >> 16) - lo; m = bf2f(p & 0xffffu);
        if ((unsigned)d < (unsigned)QSH && m != 0.f) atomicAdd(&acc[d], m);
        p = p4.y; d = (int)(p >> 16) - lo; m = bf2f(p & 0xffffu);
        if ((unsigned)d < (unsigned)QSH && m != 0.f) atomicAdd(&acc[d], m);
        p = p4.z; d = (int)(p >> 16) - lo; m = bf2f(p & 0xffffu);
        if ((unsigned)d < (unsigned)QSH && m != 0.f) atomicAdd(&acc[d], m);
        p = p4.w; d = (int)(p >> 16) - lo; m = bf2f(p & 0xffffu);
        if ((unsigned)d < (unsigned)QSH && m != 0.f) atomicAdd(&acc[d], m);
    }
    for (; i < end; i++) {              // scalar tail
        unsigned p = pk[i];
        int d = (int)(p >> 16) - lo;
        float m = bf2f(p & 0xffffu);
        if ((unsigned)d < (unsigned)QSH && m != 0.f) atomicAdd(&acc[d], m);
    }
    __syncthreads();

    // flush bf16 partials: 2 rows packed per uint, coalesced
    ushort* dst = priv + (size_t)s * (4 * QSH) + lo;
    for (int j = t * 2; j < QSH; j += 2048) {
        unsigned pkk = (unsigned)f2bf(acc[j]) | ((unsigned)f2bf(acc[j + 1]) << 16);
        *reinterpret_cast<unsigned*>(dst + j) = pkk;
    }
}

// K2C: disb[n] = bf16(rsqrt(1e-10 + sum over NSL bf16 slice partials)), packed pairs.
__global__ __launch_bounds__(256) void k2c_reduce(
    const ushort* __restrict__ priv, ushort* __restrict__ disb, int N)
{
    int n0 = (blockIdx.x * 256 + threadIdx.x) * 2;
    if (n0 >= N) return;
    float s0 = 1e-10f, s1 = 1e-10f;
    for (int p = 0; p < NSL; p++) {
        unsigned v = *reinterpret_cast<const unsigned*>(priv + (size_t)p * (4 * QSH) + n0);
        s0 += bf2f(v & 0xffffu);
        s1 += bf2f(v >> 16);
    }
    unsigned o = (unsigned)f2bf(rsqrtf(s0)) | ((unsigned)f2bf(rsqrtf(s1)) << 16);
    *reinterpret_cast<unsigned*>(disb + n0) = o;
}

// K3 (lds): stage full bf16 dis table into LDS; per-edge gathers hit LDS
// instead of the L1-miss path. 256 blocks x 1024 thr, 100KB LDS.
__global__ __launch_bounds__(1024) void k3_edge2_lds(
    const int* __restrict__ row, const int* __restrict__ col,
    float* __restrict__ out, const ushort* __restrict__ disb,
    int Npad2, int E, int EB)
{
    __shared__ ushort ldis[NMAXL];
    const int t = threadIdx.x;
    {
        const unsigned* src = reinterpret_cast<const unsigned*>(disb);
        unsigned* dst = reinterpret_cast<unsigned*>(ldis);
        const int nw = Npad2 >> 1;
        for (int i = t; i < nw; i += 1024) dst[i] = src[i];
    }
    __syncthreads();

    const int base = blockIdx.x * EB;
    int end = base + EB; if (end > E) end = E;

    int i = base + t * 4;
    for (; i + 3 < end; i += 4096) {
        int4   r4 = *reinterpret_cast<const int4*>(row + i);
        int4   c4 = *reinterpret_cast<const int4*>(col + i);
        float4 m4 = *reinterpret_cast<const float4*>(out + i);
        float4 o;
        o.x = m4.x * bf2f(ldis[r4.x]) * bf2f(ldis[c4.x]);
        o.y = m4.y * bf2f(ldis[r4.y]) * bf2f(ldis[c4.y]);
        o.z = m4.z * bf2f(ldis[r4.z]) * bf2f(ldis[c4.z]);
        o.w = m4.w * bf2f(ldis[r4.w]) * bf2f(ldis[c4.w]);
        *reinterpret_cast<float4*>(out + i) = o;
    }
    for (; i < end; i++)
        out[i] = out[i] * bf2f(ldis[row[i]]) * bf2f(ldis[col[i]]);
}

// ---- fallback path (N too large for LDS structures) ----
__global__ __launch_bounds__(256) void k2_atomic_fb(
    const int* __restrict__ row, const int* __restrict__ col,
    const float* __restrict__ values, const float* __restrict__ noise,
    const float* __restrict__ g_nb, const float* __restrict__ g_self,
    const float* __restrict__ b_att,
    float* __restrict__ out, float* __restrict__ dis, int E)
{
    int e = blockIdx.x * 256 + threadIdx.x;
    if (e >= E) return;
    int   r = row[e], c = col[e];
    float u = noise[e] + 1e-7f;
    float la = g_nb[r] + g_self[c] + b_att[0];
    float gate = u / (u + (1.f - u) * __expf(-la));
    float mask = fminf(fmaxf(gate * 1.6f - 0.5f, 0.f), 1.f);
    float m = values[e] * mask;
    out[e] = m;
    if (m != 0.f) atomicAdd(&dis[r], m);
}
__global__ __launch_bounds__(256) void k2c_rsqrt_fb(float* __restrict__ dis, int N)
{
    int n = blockIdx.x * 256 + threadIdx.x;
    if (n < N) dis[n] = rsqrtf(dis[n]);
}
__global__ __launch_bounds__(256) void k3_edge2_fb(
    const int* __restrict__ row, const int* __restrict__ col,
    float* __restrict__ out, const float* __restrict__ dis, int E)
{
    int e = blockIdx.x * 256 + threadIdx.x;
    if (e >= E) return;
    out[e] = out[e] * dis[row[e]] * dis[col[e]];
}

extern "C" void kernel_launch(void* const* d_in, const int* in_sizes, int n_in,
                              void* d_out, int out_size, void* d_ws, size_t ws_size,
                              hipStream_t stream) {
    const float* x      = (const float*)d_in[0];
    const float* W_nb   = (const float*)d_in[1];
    const float* b_nb   = (const float*)d_in[2];
    const float* W_self = (const float*)d_in[3];
    const float* b_self = (const float*)d_in[4];
    const float* W_att  = (const float*)d_in[5];
    const float* b_att  = (const float*)d_in[6];
    const float* values = (const float*)d_in[7];
    const float* noise  = (const float*)d_in[8];
    const int*   row    = (const int*)d_in[9];
    const int*   col    = (const int*)d_in[10];

    const int N = in_sizes[0] / D_DIM;
    const int E = in_sizes[7];
    float* out = (float*)d_out;

    char* ws = (char*)d_ws;
    ushort* Wt     = (ushort*)ws;                       // 131072 B
    float*  g_nb   = (float*)(ws + 131072);             // N
    float*  g_self = g_nb + N;                          // N
    float*  dis    = g_self + N;                        // N f32 (fallback) / bf16 alias
    ushort* disb   = (ushort*)dis;                      // Npad2 bf16 (lds path)
    ushort* priv   = (ushort*)(dis + N);                // NSL * 4*QSH bf16 (~12.8MB)
    size_t pk_off  = 131072 + (size_t)3 * N * 4 + (size_t)NSL * NMAXL * 2;
    pk_off = (pk_off + 15) & ~(size_t)15;
    unsigned* pk   = (unsigned*)(ws + pk_off);          // E uints (~3.2MB)

    const int Npad2 = (N + 1) & ~1;
    int ES = ((E + NSL - 1) / NSL + 3) & ~3;            // edges/slice, mult of 4
    size_t need = pk_off + (size_t)E * 4;
    bool lds_path = (N <= NMAXL) && (need <= ws_size);

    int init_n = 2 * H_DIM * D_DIM;
    if (N > init_n) init_n = N;
    k0_init<<<(init_n + 255) / 256, 256, 0, stream>>>(W_nb, W_self, Wt, dis, N, lds_path ? 0 : 1);

    const int ntiles = (N + 63) / 64;
    k1_gemm<<<256, 512, 0, stream>>>(x, Wt, b_nb, b_self, W_att, g_nb, g_self, N, ntiles);

    if (lds_path) {
        int eb4 = ((E + 3) / 4 + 255) / 256;
        k2a_gate<<<eb4, 256, 0, stream>>>(row, col, values, noise, g_nb, g_self,
                                          b_att, out, pk, E);
        k2q_scatter<<<NSL * 4, 1024, 0, stream>>>(pk, priv, E, ES);
        k2c_reduce<<<((N + 1) / 2 + 255) / 256, 256, 0, stream>>>(priv, disb, N);
        int EB = ((E + 255) / 256 + 3) & ~3;            // edges/block, mult of 4
        k3_edge2_lds<<<256, 1024, 0, stream>>>(row, col, out, disb, Npad2, E, EB);
    } else {
        k2_atomic_fb<<<(E + 255) / 256, 256, 0, stream>>>(row, col, values, noise,
                                                          g_nb, g_self, b_att, out, dis, E);
        k2c_rsqrt_fb<<<(N + 255) / 256, 256, 0, stream>>>(dis, N);
        k3_edge2_fb<<<(E + 255) / 256, 256, 0, stream>>>(row, col, out, dis, E);
    }
}

// Round 17
// 58.047 us; speedup vs baseline: 1.4456x; 1.0744x over previous
//
#include <hip/hip_runtime.h>
#include <hip/hip_bf16.h>

typedef __attribute__((ext_vector_type(8))) short bf16x8;
typedef __attribute__((ext_vector_type(4))) float f32x4;

#define D_DIM 256   // input feature dim
#define H_DIM 128   // hidden dim per branch
#define QSH 12544   // rows per quarter; LDS f32 acc = 50176 B
#define NSL 64      // edge slices (k2q grid = NSL*4 = 256 blocks, 1/CU)
#define NMAXL (4 * QSH)   // max N for lds path (=> 100352 B bf16 dis LDS)

// RNE float->bf16 (bit pattern)
__device__ inline ushort f2bf(float f) {
    union { float f; unsigned u; } a; a.f = f;
    unsigned r = a.u + 0x7fffu + ((a.u >> 16) & 1u);
    return (ushort)(r >> 16);
}
__device__ inline float bf2f(unsigned hi16) {
    union { unsigned u; float f; } a; a.u = hi16 << 16;
    return a.f;
}

// K0: build Wt in FRAGMENT-MAJOR layout (R13). Optionally init dis for fallback.
__global__ void k0_init(const float* __restrict__ W_nb, const float* __restrict__ W_self,
                        ushort* __restrict__ Wt, float* __restrict__ dis, int N, int init_dis) {
    int i = blockIdx.x * 256 + threadIdx.x;
    if (i < 2 * H_DIM * D_DIM) {
        int j    = i & 7;
        int lane = (i >> 3) & 63;
        int ks   = (i >> 9) & 7;
        int ni   = (i >> 12) & 3;
        int cg   = i >> 14;          // 0..3
        int li   = lane & 15;
        int grp  = lane >> 4;
        int h    = (cg & 1) * 64 + ni * 16 + li;
        int k    = ks * 32 + grp * 8 + j;
        const float* W = (cg >> 1) ? W_self : W_nb;
        Wt[i] = f2bf(W[k * H_DIM + h]);
    }
    if (init_dis && i < N) dis[i] = 1e-10f;
}

// K1: persistent-B fused GEMM (R13 form — coalesced frag-major Bf load).
__global__ __launch_bounds__(512, 2) void k1_gemm(
    const float* __restrict__ x, const ushort* __restrict__ Wt,
    const float* __restrict__ b_nb, const float* __restrict__ b_self,
    const float* __restrict__ W_att,
    float* __restrict__ g_nb, float* __restrict__ g_self, int N, int ntiles)
{
    __shared__ __align__(16) ushort A_lds[64][264];
    __shared__ float part[2][2][64];

    const int t    = threadIdx.x;
    const int lane = t & 63;
    const int w    = t >> 6;
    const int rh   = w >> 2;
    const int cg   = w & 3;
    const int br   = cg >> 1;
    const int ch   = cg & 1;
    const int li   = lane & 15;
    const int grp  = lane >> 4;

    float bias[4], aw[4];
    #pragma unroll
    for (int ni = 0; ni < 4; ni++) {
        int hh = ch * 64 + ni * 16 + li;
        bias[ni] = br ? b_self[hh] : b_nb[hh];
        aw[ni]   = W_att[br * H_DIM + hh];
    }

    bf16x8 Bf[4][8];
    #pragma unroll
    for (int ni = 0; ni < 4; ni++)
        #pragma unroll
        for (int ks = 0; ks < 8; ks++)
            Bf[ni][ks] = *reinterpret_cast<const bf16x8*>(
                Wt + (((size_t)(cg * 4 + ni) * 8 + ks) << 9) + lane * 8);

    const int sr = t >> 3;
    const int sc = t & 7;

    for (int rt = blockIdx.x; rt < ntiles; rt += gridDim.x) {
        const int row0 = rt * 64;

        __syncthreads();
        {
            const int gr = row0 + sr;
            const bool v = gr < N;
            const float4* src = reinterpret_cast<const float4*>(x + (size_t)gr * D_DIM);
            #pragma unroll
            for (int j = 0; j < 8; j++) {
                int c4 = sc + j * 8;
                ushort4 o;
                if (v) {
                    float4 f = src[c4];
                    o.x = f2bf(f.x); o.y = f2bf(f.y); o.z = f2bf(f.z); o.w = f2bf(f.w);
                } else { o.x = 0; o.y = 0; o.z = 0; o.w = 0; }
                *reinterpret_cast<ushort4*>(&A_lds[sr][c4 * 4]) = o;
            }
        }
        __syncthreads();

        f32x4 acc[2][4];
        #pragma unroll
        for (int mi = 0; mi < 2; mi++)
            #pragma unroll
            for (int ni = 0; ni < 4; ni++) acc[mi][ni] = f32x4{0.f, 0.f, 0.f, 0.f};

        #pragma unroll
        for (int ks = 0; ks < 8; ks++) {
            bf16x8 af0 = *reinterpret_cast<const bf16x8*>(&A_lds[rh * 32 + li][ks * 32 + grp * 8]);
            bf16x8 af1 = *reinterpret_cast<const bf16x8*>(&A_lds[rh * 32 + 16 + li][ks * 32 + grp * 8]);
            #pragma unroll
            for (int ni = 0; ni < 4; ni++) {
                acc[0][ni] = __builtin_amdgcn_mfma_f32_16x16x32_bf16(af0, Bf[ni][ks], acc[0][ni], 0, 0, 0);
                acc[1][ni] = __builtin_amdgcn_mfma_f32_16x16x32_bf16(af1, Bf[ni][ks], acc[1][ni], 0, 0, 0);
            }
        }

        float p[2][4];
        #pragma unroll
        for (int mi = 0; mi < 2; mi++)
            #pragma unroll
            for (int r4 = 0; r4 < 4; r4++) p[mi][r4] = 0.f;
        #pragma unroll
        for (int ni = 0; ni < 4; ni++)
            #pragma unroll
            for (int mi = 0; mi < 2; mi++)
                #pragma unroll
                for (int r4 = 0; r4 < 4; r4++) {
                    float y = acc[mi][ni][r4] + bias[ni];
                    y = y > 0.f ? y : 0.f;
                    p[mi][r4] += y * aw[ni];
                }
        #pragma unroll
        for (int mi = 0; mi < 2; mi++)
            #pragma unroll
            for (int r4 = 0; r4 < 4; r4++) {
                float v = p[mi][r4];
                #pragma unroll
                for (int m = 1; m < 16; m <<= 1) v += __shfl_xor(v, m);
                if (li == 0)
                    part[br][ch][rh * 32 + mi * 16 + grp * 4 + r4] = v;
            }
        __syncthreads();

        if (t < 128) {
            int b_ = t >> 6, lr = t & 63;
            int gr = row0 + lr;
            if (gr < N) {
                float val = part[b_][0][lr] + part[b_][1][lr];
                if (b_) g_self[gr] = val; else g_nb[gr] = val;
            }
        }
    }
}

// K2A: gate+mask -> pk = (row<<16)|bf16(mv) ONLY (mv carried as bf16; no f32 out
// write). 4 edges/thread, vectorized, no atomics. pk valid when N <= 65536.
__global__ __launch_bounds__(256) void k2a_gate(
    const int* __restrict__ row, const int* __restrict__ col,
    const float* __restrict__ values, const float* __restrict__ noise,
    const float* __restrict__ g_nb, const float* __restrict__ g_self,
    const float* __restrict__ b_att, unsigned* __restrict__ pk, int E)
{
    int i = (blockIdx.x * 256 + threadIdx.x) * 4;
    if (i >= E) return;
    const float ba = b_att[0];
    if (i + 3 < E) {
        int4   r4 = *reinterpret_cast<const int4*>(row + i);
        int4   c4 = *reinterpret_cast<const int4*>(col + i);
        float4 v4 = *reinterpret_cast<const float4*>(values + i);
        float4 u4 = *reinterpret_cast<const float4*>(noise + i);
        int   rr[4] = { r4.x, r4.y, r4.z, r4.w };
        int   cc[4] = { c4.x, c4.y, c4.z, c4.w };
        float vv[4] = { v4.x, v4.y, v4.z, v4.w };
        float uu[4] = { u4.x, u4.y, u4.z, u4.w };
        float gn[4], gs[4];
        #pragma unroll
        for (int j = 0; j < 4; j++) { gn[j] = g_nb[rr[j]]; gs[j] = g_self[cc[j]]; }
        unsigned pkv[4];
        #pragma unroll
        for (int j = 0; j < 4; j++) {
            float u    = uu[j] + 1e-7f;
            float la   = gn[j] + gs[j] + ba;
            float gate = u / (u + (1.f - u) * __expf(-la));
            float mask = fminf(fmaxf(gate * 1.6f - 0.5f, 0.f), 1.f);
            pkv[j] = ((unsigned)rr[j] << 16) | (unsigned)f2bf(vv[j] * mask);
        }
        *reinterpret_cast<uint4*>(pk + i) = make_uint4(pkv[0], pkv[1], pkv[2], pkv[3]);
    } else {
        for (int j = 0; j < 4 && i + j < E; j++) {
            int e = i + j;
            int   r = row[e];
            float u    = noise[e] + 1e-7f;
            float la   = g_nb[r] + g_self[col[e]] + ba;
            float gate = u / (u + (1.f - u) * __expf(-la));
            float mask = fminf(fmaxf(gate * 1.6f - 0.5f, 0.f), 1.f);
            pk[e] = ((unsigned)r << 16) | (unsigned)f2bf(values[e] * mask);
        }
    }
}

// K2Q: quartered LDS rowsum scatter over the packed stream. NSL*4 = 256 blocks
// x 1024 thr, 50KB LDS (1/CU, 16 waves). bf16 partial flush.
__global__ __launch_bounds__(1024) void k2q_scatter(
    const unsigned* __restrict__ pk, ushort* __restrict__ priv, int E, int ES)
{
    __shared__ float acc[QSH];
    const int s  = blockIdx.x >> 2;
    const int q  = blockIdx.x & 3;
    const int t  = threadIdx.x;
    const int lo = q * QSH;

    for (int i = t; i < QSH; i += 1024) acc[i] = 0.f;
    __syncthreads();

    const int base = s * ES;            // ES multiple of 4 -> 16B aligned
    int end = base + ES; if (end > E) end = E;

    int i = base + t * 4;
    for (; i + 3 < end; i += 4096) {
        uint4 p4 = *reinterpret_cast<const uint4*>(pk + i);
        unsigned p; int d; float m;
        p = p4.x; d = (int)(p >> 16) - lo; m = bf2f(p & 0xffffu);
        if ((unsigned)d < (unsigned)QSH && m != 0.f) atomicAdd(&acc[d], m);
        p = p4.y; d = (int)(p >> 16) - lo; m = bf2f(p & 0xffffu);
        if ((unsigned)d < (unsigned)QSH && m != 0.f) atomicAdd(&acc[d], m);
        p = p4.z; d = (int)(p >> 16) - lo; m = bf2f(p & 0xffffu);
        if ((unsigned)d < (unsigned)QSH && m != 0.f) atomicAdd(&acc[d], m);
        p = p4.w; d = (int)(p >> 16) - lo; m = bf2f(p & 0xffffu);
        if ((unsigned)d < (unsigned)QSH && m != 0.f) atomicAdd(&acc[d], m);
    }
    for (; i < end; i++) {              // scalar tail
        unsigned p = pk[i];
        int d = (int)(p >> 16) - lo;
        float m = bf2f(p & 0xffffu);
        if ((unsigned)d < (unsigned)QSH && m != 0.f) atomicAdd(&acc[d], m);
    }
    __syncthreads();

    // flush bf16 partials: 2 rows packed per uint, coalesced
    ushort* dst = priv + (size_t)s * (4 * QSH) + lo;
    for (int j = t * 2; j < QSH; j += 2048) {
        unsigned pkk = (unsigned)f2bf(acc[j]) | ((unsigned)f2bf(acc[j + 1]) << 16);
        *reinterpret_cast<unsigned*>(dst + j) = pkk;
    }
}

// K2C: disb[n] = bf16(rsqrt(1e-10 + sum over NSL bf16 slice partials)).
__global__ __launch_bounds__(256) void k2c_reduce(
    const ushort* __restrict__ priv, ushort* __restrict__ disb, int N)
{
    int n0 = (blockIdx.x * 256 + threadIdx.x) * 2;
    if (n0 >= N) return;
    float s0 = 1e-10f, s1 = 1e-10f;
    for (int p = 0; p < NSL; p++) {
        unsigned v = *reinterpret_cast<const unsigned*>(priv + (size_t)p * (4 * QSH) + n0);
        s0 += bf2f(v & 0xffffu);
        s1 += bf2f(v >> 16);
    }
    unsigned o = (unsigned)f2bf(rsqrtf(s0)) | ((unsigned)f2bf(rsqrtf(s1)) << 16);
    *reinterpret_cast<unsigned*>(disb + n0) = o;
}

// K3 (lds): stage full bf16 dis table into LDS; read pk (row+mv) + col; write
// out once, coalesced. 256 blocks x 1024 thr, 100KB LDS.
__global__ __launch_bounds__(1024) void k3_edge2_lds(
    const unsigned* __restrict__ pk, const int* __restrict__ col,
    float* __restrict__ out, const ushort* __restrict__ disb,
    int Npad2, int E, int EB)
{
    __shared__ ushort ldis[NMAXL];
    const int t = threadIdx.x;
    {
        const unsigned* src = reinterpret_cast<const unsigned*>(disb);
        unsigned* dst = reinterpret_cast<unsigned*>(ldis);
        const int nw = Npad2 >> 1;
        for (int i = t; i < nw; i += 1024) dst[i] = src[i];
    }
    __syncthreads();

    const int base = blockIdx.x * EB;
    int end = base + EB; if (end > E) end = E;

    int i = base + t * 4;
    for (; i + 3 < end; i += 4096) {
        uint4 p4 = *reinterpret_cast<const uint4*>(pk + i);
        int4  c4 = *reinterpret_cast<const int4*>(col + i);
        float4 o;
        o.x = bf2f(p4.x & 0xffffu) * bf2f(ldis[p4.x >> 16]) * bf2f(ldis[c4.x]);
        o.y = bf2f(p4.y & 0xffffu) * bf2f(ldis[p4.y >> 16]) * bf2f(ldis[c4.y]);
        o.z = bf2f(p4.z & 0xffffu) * bf2f(ldis[p4.z >> 16]) * bf2f(ldis[c4.z]);
        o.w = bf2f(p4.w & 0xffffu) * bf2f(ldis[p4.w >> 16]) * bf2f(ldis[c4.w]);
        *reinterpret_cast<float4*>(out + i) = o;
    }
    for (; i < end; i++) {
        unsigned p = pk[i];
        out[i] = bf2f(p & 0xffffu) * bf2f(ldis[p >> 16]) * bf2f(ldis[col[i]]);
    }
}

// ---- fallback path (N too large for LDS structures) ----
__global__ __launch_bounds__(256) void k2_atomic_fb(
    const int* __restrict__ row, const int* __restrict__ col,
    const float* __restrict__ values, const float* __restrict__ noise,
    const float* __restrict__ g_nb, const float* __restrict__ g_self,
    const float* __restrict__ b_att,
    float* __restrict__ out, float* __restrict__ dis, int E)
{
    int e = blockIdx.x * 256 + threadIdx.x;
    if (e >= E) return;
    int   r = row[e], c = col[e];
    float u = noise[e] + 1e-7f;
    float la = g_nb[r] + g_self[c] + b_att[0];
    float gate = u / (u + (1.f - u) * __expf(-la));
    float mask = fminf(fmaxf(gate * 1.6f - 0.5f, 0.f), 1.f);
    float m = values[e] * mask;
    out[e] = m;
    if (m != 0.f) atomicAdd(&dis[r], m);
}
__global__ __launch_bounds__(256) void k2c_rsqrt_fb(float* __restrict__ dis, int N)
{
    int n = blockIdx.x * 256 + threadIdx.x;
    if (n < N) dis[n] = rsqrtf(dis[n]);
}
__global__ __launch_bounds__(256) void k3_edge2_fb(
    const int* __restrict__ row, const int* __restrict__ col,
    float* __restrict__ out, const float* __restrict__ dis, int E)
{
    int e = blockIdx.x * 256 + threadIdx.x;
    if (e >= E) return;
    out[e] = out[e] * dis[row[e]] * dis[col[e]];
}

extern "C" void kernel_launch(void* const* d_in, const int* in_sizes, int n_in,
                              void* d_out, int out_size, void* d_ws, size_t ws_size,
                              hipStream_t stream) {
    const float* x      = (const float*)d_in[0];
    const float* W_nb   = (const float*)d_in[1];
    const float* b_nb   = (const float*)d_in[2];
    const float* W_self = (const float*)d_in[3];
    const float* b_self = (const float*)d_in[4];
    const float* W_att  = (const float*)d_in[5];
    const float* b_att  = (const float*)d_in[6];
    const float* values = (const float*)d_in[7];
    const float* noise  = (const float*)d_in[8];
    const int*   row    = (const int*)d_in[9];
    const int*   col    = (const int*)d_in[10];

    const int N = in_sizes[0] / D_DIM;
    const int E = in_sizes[7];
    float* out = (float*)d_out;

    char* ws = (char*)d_ws;
    ushort* Wt     = (ushort*)ws;                       // 131072 B
    float*  g_nb   = (float*)(ws + 131072);             // N
    float*  g_self = g_nb + N;                          // N
    float*  dis    = g_self + N;                        // N f32 (fallback) / bf16 alias
    ushort* disb   = (ushort*)dis;                      // Npad2 bf16 (lds path)
    ushort* priv   = (ushort*)(dis + N);                // NSL * NMAXL bf16 (~6.4MB)
    size_t pk_off  = 131072 + (size_t)3 * N * 4 + (size_t)NSL * NMAXL * 2;
    pk_off = (pk_off + 15) & ~(size_t)15;
    unsigned* pk   = (unsigned*)(ws + pk_off);          // E uints (~3.2MB)

    const int Npad2 = (N + 1) & ~1;
    int ES = ((E + NSL - 1) / NSL + 3) & ~3;            // edges/slice, mult of 4
    size_t need = pk_off + (size_t)E * 4;
    bool lds_path = (N <= NMAXL) && (need <= ws_size);

    int init_n = 2 * H_DIM * D_DIM;
    if (N > init_n) init_n = N;
    k0_init<<<(init_n + 255) / 256, 256, 0, stream>>>(W_nb, W_self, Wt, dis, N, lds_path ? 0 : 1);

    const int ntiles = (N + 63) / 64;
    k1_gemm<<<256, 512, 0, stream>>>(x, Wt, b_nb, b_self, W_att, g_nb, g_self, N, ntiles);

    if (lds_path) {
        int eb4 = ((E + 3) / 4 + 255) / 256;
        k2a_gate<<<eb4, 256, 0, stream>>>(row, col, values, noise, g_nb, g_self,
                                          b_att, pk, E);
        k2q_scatter<<<NSL * 4, 1024, 0, stream>>>(pk, priv, E, ES);
        k2c_reduce<<<((N + 1) / 2 + 255) / 256, 256, 0, stream>>>(priv, disb, N);
        int EB = ((E + 255) / 256 + 3) & ~3;            // edges/block, mult of 4
        k3_edge2_lds<<<256, 1024, 0, stream>>>(pk, col, out, disb, Npad2, E, EB);
    } else {
        k2_atomic_fb<<<(E + 255) / 256, 256, 0, stream>>>(row, col, values, noise,
                                                          g_nb, g_self, b_att, out, dis, E);
        k2c_rsqrt_fb<<<(N + 255) / 256, 256, 0, stream>>>(dis, N);
        k3_edge2_fb<<<(E + 255) / 256, 256, 0, stream>>>(row, col, out, dis, E);
    }
}